// Round 5
// baseline (432.511 us; speedup 1.0000x reference)
//
#include <hip/hip_runtime.h>
#include <hip/hip_bf16.h>
#include <cstdint>

// ---------------------------------------------------------------------------
// AdaptiveMixing fused kernel set, R10 (= R9 with the bit_cast compile fix).
// R9/R10 changes vs R8 (occupancy + VALU round; no structural change):
//  - Hb (2 KB, dead after step 3) aliased into g2t (first written dt=1):
//    LDS 72704 -> ~70528 B. Theory: usable LDS pool is ~144 KB/CU, so R8's
//    72.7 KB x2 = 145.4 KB missed 2-block residency by 1.4 KB (Occupancy
//    counter read ~23% ~= 1 block/CU). 70.5 KB x2 = 141 KB fits.
//  - __launch_bounds__(512, 4): pin 4 waves/SIMD (2 blocks/CU) so the
//    allocator targets the 128-VGPR tier (R8 chose 124 naturally -> fits).
//  - All bf16 packing via __float22bfloat162_rn (official RNE API, lowers to
//    v_cvt_pk_bf16_f32); extracted via __builtin_memcpy (bit_cast rejects
//    the non-trivially-copyable __hip_bfloat162).
// Layouts (unchanged from R8):
//   w2p  [cb][d][ks][lane][8], w2sp [g][ks][lane][8], w1p [nb][ks][lane][8],
//   wop  [kc5][nb][lane][8]  (kc5 = dcol of wo; k'' = o)
// MFMA 16x16x32_bf16: A/B: idx lane&15, k=(lane>>4)*8+j; C/D: col=lane&15,
// row=(lane>>4)*4+i.
// ---------------------------------------------------------------------------

typedef __bf16 bf16x8 __attribute__((ext_vector_type(8)));
typedef float  f32x4  __attribute__((ext_vector_type(4)));
typedef unsigned short ushort;
typedef ushort ushort8 __attribute__((ext_vector_type(8)));

#define TW 16     // tokens per fused workgroup

// RNE f32->bf16 via the official intrinsic (lowers to v_cvt_pk_bf16_f32).
// memcpy (not bit_cast): __hip_bfloat162 is not trivially copyable per clang.
__device__ __forceinline__ uint32_t pk2(float a, float b) {
    __hip_bfloat162 h = __float22bfloat162_rn(make_float2(a, b));
    uint32_t r;
    __builtin_memcpy(&r, &h, 4);
    return r;
}
__device__ __forceinline__ ushort f2b(float f) {
    return (ushort)pk2(f, f);
}
__device__ __forceinline__ bf16x8 cvt8(float4 lo, float4 hi) {
    uint4 u;
    u.x = pk2(lo.x, lo.y); u.y = pk2(lo.z, lo.w);
    u.z = pk2(hi.x, hi.y); u.w = pk2(hi.z, hi.w);
    return __builtin_bit_cast(bf16x8, u);
}
// Abramowitz-Stegun 7.1.26 erf (|err|<=1.5e-7), branchless; gelu exact form.
__device__ __forceinline__ float gelu_fast(float x) {
    float z = fabsf(x) * 0.70710678118654752440f;
    float t = __builtin_amdgcn_rcpf(fmaf(0.3275911f, z, 1.0f));
    float p = t * fmaf(t, fmaf(t, fmaf(t, fmaf(t, 1.061405429f, -1.453152027f),
                                       1.421413741f), -0.284496736f), 0.254829592f);
    float e = __expf(-z * z);
    float erfv = copysignf(fmaf(-p, e, 1.0f), x);
    return 0.5f * x * (1.0f + erfv);
}

// g2t swizzle: shared by spatial write and outacc read. byte in [0,64).
// Bijective on the 16KB tile (bits 4-6 XORed by f(t,d16); recoverable).
__device__ __forceinline__ int g2swz(int t, int d16, int byte) {
    return (t * 1024 + d16 * 64 + byte) ^ (((t ^ d16) & 7) << 4);
}

// ---------------------------------------------------------------------------
// prep: coalesced permutes. 1080 blocks x 256 threads, block-range split.
__global__ void prep(const float* __restrict__ w2, const float* __restrict__ w1,
                     const float* __restrict__ wo, const float* __restrict__ b2,
                     ushort* __restrict__ w2p, ushort* __restrict__ w2sp,
                     ushort* __restrict__ w1p, ushort* __restrict__ wop,
                     float* __restrict__ b2t) {
    const int blk = blockIdx.x, tid = threadIdx.x;
    if (blk < 512) {
        // i8 = ((cb*128+d)*2+ks)*64 + l ; out = w2p[i8*8 .. +7]
        int i8 = blk * 256 + tid;
        int l = i8 & 63, ks = (i8 >> 6) & 1, d = (i8 >> 7) & 127, cb = i8 >> 14;
        int c = cb * 16 + (l & 15);
        const float* src = w2 + (size_t)(c * 128 + d) * 64 + ks * 32 + (l >> 4) * 8;
        bf16x8 u = cvt8(*(const float4*)src, *(const float4*)(src + 4));
        *(bf16x8*)&w2p[(size_t)i8 * 8] = u;
    } else if (blk < 1024) {
        // wop[kc5=dcol][nb=q>>4][l=(o3<<4)|(q&15)][j] = wo[q][o3*8+j][dcol]
        int t8 = (blk - 512) * 256 + tid;
        int dcol = t8 & 127, o3 = (t8 >> 7) & 3, q = t8 >> 9;
        const float* src = wo + (size_t)q * 4096 + o3 * 1024 + dcol;
        float4 lo, hi;
        lo.x = src[0 * 128]; lo.y = src[1 * 128]; lo.z = src[2 * 128]; lo.w = src[3 * 128];
        hi.x = src[4 * 128]; hi.y = src[5 * 128]; hi.z = src[6 * 128]; hi.w = src[7 * 128];
        bf16x8 u = cvt8(lo, hi);
        *(bf16x8*)&wop[(size_t)dcol * 8192 + (q >> 4) * 512 + (q & 15) * 8 + o3 * 128] = u;
    } else if (blk < 1056) {
        // w2sp: i8 = g<<7 | ks<<6 | l
        int t = (blk - 1024) * 256 + tid;          // [0, 8192)
        int l = t & 63, ks = (t >> 6) & 1, g = t >> 7;
        const float* src = w2 + (size_t)(16384 + g * 16 + (l & 15)) * 64 +
                           ks * 32 + (l >> 4) * 8;
        bf16x8 u = cvt8(*(const float4*)src, *(const float4*)(src + 4));
        *(bf16x8*)&w2sp[(size_t)t * 8] = u;
    } else if (blk < 1064) {
        // w1p: i8 = nb<<9 | ks<<6 | l
        int t = (blk - 1056) * 256 + tid;          // [0, 2048)
        int l = t & 63, ks = (t >> 6) & 7, nb = t >> 9;
        const float* src = w1 + (nb * 16 + (l & 15)) * 256 + ks * 32 + (l >> 4) * 8;
        bf16x8 u = cvt8(*(const float4*)src, *(const float4*)(src + 4));
        *(bf16x8*)&w1p[(size_t)t * 8] = u;
    } else {
        // b2t[d][c] = b2[c][d]; lanes vary d -> coalesced reads
        int t = (blk - 1064) * 256 + tid;          // [0, 4096)
        int d = t & 127, c4 = t >> 7;
        float4 r;
        r.x = b2[(c4 * 4 + 0) * 128 + d];
        r.y = b2[(c4 * 4 + 1) * 128 + d];
        r.z = b2[(c4 * 4 + 2) * 128 + d];
        r.w = b2[(c4 * 4 + 3) * 128 + d];
        *(float4*)&b2t[d * 128 + c4 * 4] = r;
    }
}

// ---------------------------------------------------------------------------
__launch_bounds__(512, 4)
__global__ void fused(const float* __restrict__ sampled, const float* __restrict__ query,
                      const float* __restrict__ ln_w, const float* __restrict__ ln_b,
                      const float* __restrict__ b1, const float* __restrict__ b2,
                      const float* __restrict__ m_beta, const float* __restrict__ s_beta,
                      const ushort* __restrict__ w2p, const ushort* __restrict__ w2sp,
                      const ushort* __restrict__ w1p, const float* __restrict__ b2t,
                      const ushort* __restrict__ wop, const float* __restrict__ bo,
                      float* __restrict__ out) {
    __shared__ union {
        ushort qn[TW * 264];                             // phase 1: LN out
        ushort smT[TW * 1032];                           // phase 2: sm [t][o*32+p]
        struct {
            ushort pt[TW * 1032];                        // [t][chunk(c>>3,dd)][c&7]
            ushort g1s[TW * 640];                        // [t][d16*40+p]
        } mp;                                            // main loop
    } U;
    // Hb (h bf16 [t][64], dead after step-3 hfr loads) aliases g2t (first
    // written at dt=1 spatial) -> saves 2 KB, gets LDS under the 2-block
    // residency line. g2t XOR-swizzled via g2swz (both sides).
    __shared__ __align__(16) union {
        ushort Hb[TW * 64];                              // steps 2-3
        ushort g2t[TW * 16 * 32];                        // main loop, 16384 B
    } G;
    __shared__ float mb_s[128];
    __shared__ float sb_s[32];

    const int tid  = threadIdx.x;
    const int wv   = tid >> 6;          // wave 0..7
    const int lane = tid & 63;
    const int lq   = lane >> 4;         // quad
    const int ln16 = lane & 15;
    const int tok0 = blockIdx.x * TW;

    if (tid < 128) mb_s[tid] = m_beta[tid];
    else if (tid < 160) sb_s[tid - 128] = s_beta[tid - 128];

    // ---- step 1: LayerNorm, 2 tokens per wave; qn -> LDS bf16 (row 264)
    for (int tt = 0; tt < 2; ++tt) {
        int t = wv * 2 + tt;
        const float* q = query + (size_t)(tok0 + t) * 256;
        float2 a = *(const float2*)(q + 2 * lane);
        float2 b = *(const float2*)(q + 128 + 2 * lane);
        float s = a.x + a.y + b.x + b.y;
        for (int off = 1; off < 64; off <<= 1) s += __shfl_xor(s, off);
        float mu = s * (1.0f / 256.0f);
        float d0 = a.x - mu, d1 = a.y - mu, d2 = b.x - mu, d3 = b.y - mu;
        float ss = d0 * d0 + d1 * d1 + d2 * d2 + d3 * d3;
        for (int off = 1; off < 64; off <<= 1) ss += __shfl_xor(ss, off);
        float rstd = rsqrtf(ss * (1.0f / 256.0f) + 1e-6f);
        int i0 = 2 * lane, i1 = 2 * lane + 128;
        float q0 = d0 * rstd * ln_w[i0]     + ln_b[i0];
        float q1 = d1 * rstd * ln_w[i0 + 1] + ln_b[i0 + 1];
        float q2 = d2 * rstd * ln_w[i1]     + ln_b[i1];
        float q3 = d3 * rstd * ln_w[i1 + 1] + ln_b[i1 + 1];
        *(uint32_t*)&U.qn[t * 264 + i0] = pk2(q0, q1);
        *(uint32_t*)&U.qn[t * 264 + i1] = pk2(q2, q3);
    }
    __syncthreads();

    // ---- step 2: h[16 tok][64] = qn @ w1^T + b1 (waves 0..3)
    if (wv < 4) {
        int nb = wv;
        f32x4 acc = {0.0f, 0.0f, 0.0f, 0.0f};
        for (int ks = 0; ks < 8; ++ks) {
            bf16x8 afr = *(const bf16x8*)&U.qn[ln16 * 264 + ks * 32 + lq * 8];
            bf16x8 bfr = *(const bf16x8*)&w1p[(nb * 8 + ks) * 512 + lane * 8];
            acc = __builtin_amdgcn_mfma_f32_16x16x32_bf16(afr, bfr, acc, 0, 0, 0);
        }
        float bias = b1[nb * 16 + ln16];
        for (int i = 0; i < 4; ++i) {
            int t = lq * 4 + i;                      // D row = token
            G.Hb[t * 64 + nb * 16 + ln16] = f2b(acc[i] + bias);
        }
    }
    __syncthreads();

    // ---- step 3: H B-frags; sm generation -> smT; x A-frag hoist
    bf16x8 hfr[2];
    hfr[0] = *(const bf16x8*)&G.Hb[ln16 * 64 + 0 + lq * 8];
    hfr[1] = *(const bf16x8*)&G.Hb[ln16 * 64 + 32 + lq * 8];

    for (int gi = 0; gi < 8; ++gi) {                 // sm rows 16384 + g*16 + m
        int g = wv * 8 + gi;
        f32x4 acc = *(const f32x4*)&b2[16384 + g * 16 + lq * 4];
        for (int ks = 0; ks < 2; ++ks) {
            bf16x8 afr = *(const bf16x8*)&w2sp[(g * 2 + ks) * 512 + lane * 8];
            acc = __builtin_amdgcn_mfma_f32_16x16x32_bf16(afr, hfr[ks], acc, 0, 0, 0);
        }
        int o = g >> 1;
        int p0 = (g & 1) * 16 + lq * 4;
        uint2 wr;
        wr.x = pk2(acc[0], acc[1]);
        wr.y = pk2(acc[2], acc[3]);
        *(uint2*)&U.smT[ln16 * 1032 + o * 32 + p0] = wr;   // token-major
    }

    bf16x8 xa[2][2][4];                              // x A-frags [tt][p-half][ks]
    for (int tt = 0; tt < 2; ++tt) {
        const float* xp = sampled + (size_t)(tok0 + wv * 2 + tt) * 4096;
        for (int mt = 0; mt < 2; ++mt) {
            int p = mt * 16 + ln16;
            for (int ks = 0; ks < 4; ++ks) {
                int c = ks * 32 + lq * 8;
                xa[tt][mt][ks] = cvt8(*(const float4*)(xp + p * 128 + c),
                                      *(const float4*)(xp + p * 128 + c + 4));
            }
        }
    }
    __syncthreads();

    // ---- step 4: sm A-frags (K=32) for this wave's 2 tokens
    bf16x8 sa[2][2];
    for (int tt = 0; tt < 2; ++tt) {
        int t = wv * 2 + tt;
        for (int mt = 0; mt < 2; ++mt)
            sa[tt][mt] = *(const bf16x8*)&U.smT[t * 1032 + (mt * 16 + ln16) * 32 + lq * 8];
    }
    __syncthreads();    // smT dead; pt/g1s alias it from here on

    // out-projection accumulator: 16 tok x 32 q per wave (nb = 2wv, 2wv+1)
    f32x4 aco[2] = {(f32x4){0.0f, 0.0f, 0.0f, 0.0f}, (f32x4){0.0f, 0.0f, 0.0f, 0.0f}};

    // OUTACC(dt2): aco += g2t(tile dt2) @ wop. A: row=t(ln16), k=o(lq*8+j);
    // B: wop[kc5=dt2*16+d16][nb][lane][8]. Depth-1 register prefetch of the
    // wop B-frags hides L2 latency under the 2 MFMAs per step.
    auto outacc = [&](int dt2) {
        const ushort* wb = wop + ((size_t)(dt2 * 16) * 16 + wv * 2) * 512 + lane * 8;
        bf16x8 nb0 = *(const bf16x8*)(wb);
        bf16x8 nb1 = *(const bf16x8*)(wb + 512);
        for (int d16 = 0; d16 < 16; ++d16) {
            bf16x8 b0 = nb0, b1 = nb1;
            if (d16 < 15) {
                nb0 = *(const bf16x8*)(wb + (size_t)(d16 + 1) * 8192);
                nb1 = *(const bf16x8*)(wb + (size_t)(d16 + 1) * 8192 + 512);
            }
            bf16x8 afr = *(const bf16x8*)((const char*)G.g2t + g2swz(ln16, d16, lq * 16));
            aco[0] = __builtin_amdgcn_mfma_f32_16x16x32_bf16(afr, b0, aco[0], 0, 0, 0);
            aco[1] = __builtin_amdgcn_mfma_f32_16x16x32_bf16(afr, b1, aco[1], 0, 0, 0);
        }
    };

    // ---- main loop over 16 d-tiles of width 8; spatial every 2nd tile
    for (int dt = 0; dt < 16; ++dt) {
        // OUTACC for the tile completed at dt-1 (past the trailing barrier;
        // next g2t write is 2 barriers away -> race-free, overlaps GEN loads)
        if (dt && !(dt & 1)) outacc((dt >> 1) - 1);

        // GEN: wave wv owns c-block cb=wv; P[c, token] for d = dt*8+dd
        const int cb = wv;
        for (int dd = 0; dd < 8; ++dd) {
            int d = dt * 8 + dd;
            // bias: b2t[d][c], c = cb*16 + lq*4 + i -> one broadcast f32x4
            f32x4 acc = *(const f32x4*)&b2t[d * 128 + cb * 16 + lq * 4];
            for (int ks = 0; ks < 2; ++ks) {
                bf16x8 afr = *(const bf16x8*)&w2p[((cb * 128 + d) * 2 + ks) * 512 + lane * 8];
                acc = __builtin_amdgcn_mfma_f32_16x16x32_bf16(afr, hfr[ks], acc, 0, 0, 0);
            }
            // lane-linear pt: token=ln16, chunk=(c>>3)*8+dd, j=c&7
            uint2 wr;
            wr.x = pk2(acc[0], acc[1]);
            wr.y = pk2(acc[2], acc[3]);
            *(uint2*)&U.mp.pt[ln16 * 1032 + ((cb * 2 + (lq >> 1)) * 8 + dd) * 8 + (lq & 1) * 4] = wr;
        }
        __syncthreads();

        // CONSUME channel: 2 tokens per wave. Lanes n>=8 duplicate n-8's acc;
        // split gelu rows {0,1}/{2,3} across the halves (branchless).
        const int ddl = ln16 & 7;
        const bool hi = ln16 >= 8;
        for (int tt = 0; tt < 2; ++tt) {
            int t = wv * 2 + tt;
            bf16x8 bfr[4];
            for (int ks = 0; ks < 4; ++ks)
                bfr[ks] = *(const bf16x8*)&U.mp.pt[t * 1032 + (ks * 4 + lq) * 64 + ddl * 8];
            float mb = mb_s[dt * 8 + ddl];
            for (int mt = 0; mt < 2; ++mt) {
                f32x4 acc = {0.0f, 0.0f, 0.0f, 0.0f};
                for (int ks = 0; ks < 4; ++ks)
                    acc = __builtin_amdgcn_mfma_f32_16x16x32_bf16(xa[tt][mt][ks], bfr[ks], acc, 0, 0, 0);
                float va = hi ? acc[2] : acc[0];
                float vb = hi ? acc[3] : acc[1];
                float ga = gelu_fast(va + mb);
                float gb = gelu_fast(vb + mb);
                // g1s[t][d16][p]: d16 = (dt&1)*8+ddl; rows p0..p0+1 by lo half,
                // p0+2..p0+3 by hi half
                int p = mt * 16 + lq * 4 + (hi ? 2 : 0);
                *(uint32_t*)&U.mp.g1s[t * 640 + ((dt & 1) * 8 + ddl) * 40 + p] = pk2(ga, gb);
            }
        }

        // SPATIAL on odd dt: full 16-lane n over paired d16 = 0..15
        if (dt & 1) {
            __builtin_amdgcn_wave_barrier();          // order same-wave LDS W->R
            for (int tt = 0; tt < 2; ++tt) {
                int t = wv * 2 + tt;
                bf16x8 gfr = *(const bf16x8*)&U.mp.g1s[t * 640 + ln16 * 40 + lq * 8];
                for (int mt = 0; mt < 2; ++mt) {
                    f32x4 acc = {0.0f, 0.0f, 0.0f, 0.0f};
                    acc = __builtin_amdgcn_mfma_f32_16x16x32_bf16(sa[tt][mt], gfr, acc, 0, 0, 0);
                    float4 sbv = *(const float4*)&sb_s[mt * 16 + lq * 4];
                    float g0 = gelu_fast(acc[0] + sbv.x);
                    float g1 = gelu_fast(acc[1] + sbv.y);
                    float g2 = gelu_fast(acc[2] + sbv.z);
                    float g3 = gelu_fast(acc[3] + sbv.w);
                    uint2 wr;
                    wr.x = pk2(g0, g1);
                    wr.y = pk2(g2, g3);
                    // g2t[t][d16=ln16][o = mt*16+lq*4 ..+3], swizzled (8B write:
                    // byte bit3 = lq&1 untouched; XOR hits bits 4-6 only)
                    *(uint2*)((char*)G.g2t + g2swz(t, ln16, mt * 32 + lq * 8)) = wr;
                }
            }
        }
        __syncthreads();
    }

    // last g2 tile (dt2 = 7), then out = aco + bo. D row = token, col = q.
    outacc(7);
    for (int n = 0; n < 2; ++n) {
        int q = (wv * 2 + n) * 16 + ln16;
        float bv = bo[q];
        for (int i = 0; i < 4; ++i) {
            int tok = tok0 + lq * 4 + i;
            out[(size_t)tok * 256 + q] = aco[n][i] + bv;
        }
    }
}

// ---------------------------------------------------------------------------
extern "C" void kernel_launch(void* const* d_in, const int* in_sizes, int n_in,
                              void* d_out, int out_size, void* d_ws, size_t ws_size,
                              hipStream_t stream) {
    const float* sampled = (const float*)d_in[0];
    const float* query   = (const float*)d_in[1];
    const float* ln_w    = (const float*)d_in[2];
    const float* ln_b    = (const float*)d_in[3];
    const float* w1      = (const float*)d_in[4];
    const float* b1      = (const float*)d_in[5];
    const float* w2      = (const float*)d_in[6];
    const float* b2      = (const float*)d_in[7];
    const float* m_beta  = (const float*)d_in[8];
    const float* s_beta  = (const float*)d_in[9];
    const float* wo      = (const float*)d_in[10];
    const float* bo      = (const float*)d_in[11];
    float* out = (float*)d_out;

    char* ws = (char*)d_ws;
    ushort* w2p  = (ushort*)(ws);                   // 2,097,152 B
    ushort* wop  = (ushort*)(ws + 2097152);         // 2,097,152 B
    ushort* w2sp = (ushort*)(ws + 4194304);         //   131,072 B
    ushort* w1p  = (ushort*)(ws + 4325376);         //    32,768 B
    float*  b2t  = (float*) (ws + 4358144);         //    65,536 B (total ~4.4 MB)

    prep<<<1080, 256, 0, stream>>>(w2, w1, wo, b2, w2p, w2sp, w1p, wop, b2t);
    fused<<<512, 512, 0, stream>>>(sampled, query, ln_w, ln_b, b1, b2,
                                   m_beta, s_beta, w2p, w2sp, w1p, b2t,
                                   wop, bo, out);
}

// Round 6
// 378.739 us; speedup vs baseline: 1.1420x; 1.1420x over previous
//
#include <hip/hip_runtime.h>
#include <hip/hip_bf16.h>
#include <cstdint>

// ---------------------------------------------------------------------------
// AdaptiveMixing fused kernel set, R11.
// R11 = R10 with __launch_bounds__(512, 2) restored.
// R10's decisive experiment:
//  - LDS alias (Hb into g2t): 72704 -> 70656 B => 2 blocks/CU RESIDENT
//    (Occupancy 23 -> 44%). Usable LDS pool/CU is in [141312, 145408) B.
//  - __launch_bounds__(512,4): hipcc used CUDA semantics (min BLOCKS/CU):
//    4 blocks x 8 waves = 32 waves/CU -> 64-VGPR cap -> massive scratch
//    spills (FETCH 104->310 MB, WRITE 8->93 MB). (512,2) -> 16 waves/CU ->
//    128-VGPR cap; R8 measured 124 with no spills. Keep (512,2).
//  - bf16 packing via __float22bfloat162_rn (v_cvt_pk_bf16_f32), extracted
//    with __builtin_memcpy.
// Layouts (unchanged):
//   w2p  [cb][d][ks][lane][8], w2sp [g][ks][lane][8], w1p [nb][ks][lane][8],
//   wop  [kc5][nb][lane][8]  (kc5 = dcol of wo; k'' = o)
// MFMA 16x16x32_bf16: A/B: idx lane&15, k=(lane>>4)*8+j; C/D: col=lane&15,
// row=(lane>>4)*4+i.
// ---------------------------------------------------------------------------

typedef __bf16 bf16x8 __attribute__((ext_vector_type(8)));
typedef float  f32x4  __attribute__((ext_vector_type(4)));
typedef unsigned short ushort;
typedef ushort ushort8 __attribute__((ext_vector_type(8)));

#define TW 16     // tokens per fused workgroup

// RNE f32->bf16 via the official intrinsic (lowers to v_cvt_pk_bf16_f32).
// memcpy (not bit_cast): __hip_bfloat162 is not trivially copyable per clang.
__device__ __forceinline__ uint32_t pk2(float a, float b) {
    __hip_bfloat162 h = __float22bfloat162_rn(make_float2(a, b));
    uint32_t r;
    __builtin_memcpy(&r, &h, 4);
    return r;
}
__device__ __forceinline__ ushort f2b(float f) {
    return (ushort)pk2(f, f);
}
__device__ __forceinline__ bf16x8 cvt8(float4 lo, float4 hi) {
    uint4 u;
    u.x = pk2(lo.x, lo.y); u.y = pk2(lo.z, lo.w);
    u.z = pk2(hi.x, hi.y); u.w = pk2(hi.z, hi.w);
    return __builtin_bit_cast(bf16x8, u);
}
// Abramowitz-Stegun 7.1.26 erf (|err|<=1.5e-7), branchless; gelu exact form.
__device__ __forceinline__ float gelu_fast(float x) {
    float z = fabsf(x) * 0.70710678118654752440f;
    float t = __builtin_amdgcn_rcpf(fmaf(0.3275911f, z, 1.0f));
    float p = t * fmaf(t, fmaf(t, fmaf(t, fmaf(t, 1.061405429f, -1.453152027f),
                                       1.421413741f), -0.284496736f), 0.254829592f);
    float e = __expf(-z * z);
    float erfv = copysignf(fmaf(-p, e, 1.0f), x);
    return 0.5f * x * (1.0f + erfv);
}

// g2t swizzle: shared by spatial write and outacc read. byte in [0,64).
// Bijective on the 16KB tile (bits 4-6 XORed by f(t,d16); recoverable).
__device__ __forceinline__ int g2swz(int t, int d16, int byte) {
    return (t * 1024 + d16 * 64 + byte) ^ (((t ^ d16) & 7) << 4);
}

// ---------------------------------------------------------------------------
// prep: coalesced permutes. 1080 blocks x 256 threads, block-range split.
__global__ void prep(const float* __restrict__ w2, const float* __restrict__ w1,
                     const float* __restrict__ wo, const float* __restrict__ b2,
                     ushort* __restrict__ w2p, ushort* __restrict__ w2sp,
                     ushort* __restrict__ w1p, ushort* __restrict__ wop,
                     float* __restrict__ b2t) {
    const int blk = blockIdx.x, tid = threadIdx.x;
    if (blk < 512) {
        // i8 = ((cb*128+d)*2+ks)*64 + l ; out = w2p[i8*8 .. +7]
        int i8 = blk * 256 + tid;
        int l = i8 & 63, ks = (i8 >> 6) & 1, d = (i8 >> 7) & 127, cb = i8 >> 14;
        int c = cb * 16 + (l & 15);
        const float* src = w2 + (size_t)(c * 128 + d) * 64 + ks * 32 + (l >> 4) * 8;
        bf16x8 u = cvt8(*(const float4*)src, *(const float4*)(src + 4));
        *(bf16x8*)&w2p[(size_t)i8 * 8] = u;
    } else if (blk < 1024) {
        // wop[kc5=dcol][nb=q>>4][l=(o3<<4)|(q&15)][j] = wo[q][o3*8+j][dcol]
        int t8 = (blk - 512) * 256 + tid;
        int dcol = t8 & 127, o3 = (t8 >> 7) & 3, q = t8 >> 9;
        const float* src = wo + (size_t)q * 4096 + o3 * 1024 + dcol;
        float4 lo, hi;
        lo.x = src[0 * 128]; lo.y = src[1 * 128]; lo.z = src[2 * 128]; lo.w = src[3 * 128];
        hi.x = src[4 * 128]; hi.y = src[5 * 128]; hi.z = src[6 * 128]; hi.w = src[7 * 128];
        bf16x8 u = cvt8(lo, hi);
        *(bf16x8*)&wop[(size_t)dcol * 8192 + (q >> 4) * 512 + (q & 15) * 8 + o3 * 128] = u;
    } else if (blk < 1056) {
        // w2sp: i8 = g<<7 | ks<<6 | l
        int t = (blk - 1024) * 256 + tid;          // [0, 8192)
        int l = t & 63, ks = (t >> 6) & 1, g = t >> 7;
        const float* src = w2 + (size_t)(16384 + g * 16 + (l & 15)) * 64 +
                           ks * 32 + (l >> 4) * 8;
        bf16x8 u = cvt8(*(const float4*)src, *(const float4*)(src + 4));
        *(bf16x8*)&w2sp[(size_t)t * 8] = u;
    } else if (blk < 1064) {
        // w1p: i8 = nb<<9 | ks<<6 | l
        int t = (blk - 1056) * 256 + tid;          // [0, 2048)
        int l = t & 63, ks = (t >> 6) & 7, nb = t >> 9;
        const float* src = w1 + (nb * 16 + (l & 15)) * 256 + ks * 32 + (l >> 4) * 8;
        bf16x8 u = cvt8(*(const float4*)src, *(const float4*)(src + 4));
        *(bf16x8*)&w1p[(size_t)t * 8] = u;
    } else {
        // b2t[d][c] = b2[c][d]; lanes vary d -> coalesced reads
        int t = (blk - 1064) * 256 + tid;          // [0, 4096)
        int d = t & 127, c4 = t >> 7;
        float4 r;
        r.x = b2[(c4 * 4 + 0) * 128 + d];
        r.y = b2[(c4 * 4 + 1) * 128 + d];
        r.z = b2[(c4 * 4 + 2) * 128 + d];
        r.w = b2[(c4 * 4 + 3) * 128 + d];
        *(float4*)&b2t[d * 128 + c4 * 4] = r;
    }
}

// ---------------------------------------------------------------------------
__launch_bounds__(512, 2)
__global__ void fused(const float* __restrict__ sampled, const float* __restrict__ query,
                      const float* __restrict__ ln_w, const float* __restrict__ ln_b,
                      const float* __restrict__ b1, const float* __restrict__ b2,
                      const float* __restrict__ m_beta, const float* __restrict__ s_beta,
                      const ushort* __restrict__ w2p, const ushort* __restrict__ w2sp,
                      const ushort* __restrict__ w1p, const float* __restrict__ b2t,
                      const ushort* __restrict__ wop, const float* __restrict__ bo,
                      float* __restrict__ out) {
    __shared__ union {
        ushort qn[TW * 264];                             // phase 1: LN out
        ushort smT[TW * 1032];                           // phase 2: sm [t][o*32+p]
        struct {
            ushort pt[TW * 1032];                        // [t][chunk(c>>3,dd)][c&7]
            ushort g1s[TW * 640];                        // [t][d16*40+p]
        } mp;                                            // main loop
    } U;
    // Hb (h bf16 [t][64], dead after step-3 hfr loads) aliases g2t (first
    // written at dt=1 spatial) -> keeps LDS at 70656 B: 2 blocks/CU resident
    // (proven R10: Occupancy 44%). g2t XOR-swizzled via g2swz (both sides).
    __shared__ __align__(16) union {
        ushort Hb[TW * 64];                              // steps 2-3
        ushort g2t[TW * 16 * 32];                        // main loop, 16384 B
    } G;
    __shared__ float mb_s[128];
    __shared__ float sb_s[32];

    const int tid  = threadIdx.x;
    const int wv   = tid >> 6;          // wave 0..7
    const int lane = tid & 63;
    const int lq   = lane >> 4;         // quad
    const int ln16 = lane & 15;
    const int tok0 = blockIdx.x * TW;

    if (tid < 128) mb_s[tid] = m_beta[tid];
    else if (tid < 160) sb_s[tid - 128] = s_beta[tid - 128];

    // ---- step 1: LayerNorm, 2 tokens per wave; qn -> LDS bf16 (row 264)
    for (int tt = 0; tt < 2; ++tt) {
        int t = wv * 2 + tt;
        const float* q = query + (size_t)(tok0 + t) * 256;
        float2 a = *(const float2*)(q + 2 * lane);
        float2 b = *(const float2*)(q + 128 + 2 * lane);
        float s = a.x + a.y + b.x + b.y;
        for (int off = 1; off < 64; off <<= 1) s += __shfl_xor(s, off);
        float mu = s * (1.0f / 256.0f);
        float d0 = a.x - mu, d1 = a.y - mu, d2 = b.x - mu, d3 = b.y - mu;
        float ss = d0 * d0 + d1 * d1 + d2 * d2 + d3 * d3;
        for (int off = 1; off < 64; off <<= 1) ss += __shfl_xor(ss, off);
        float rstd = rsqrtf(ss * (1.0f / 256.0f) + 1e-6f);
        int i0 = 2 * lane, i1 = 2 * lane + 128;
        float q0 = d0 * rstd * ln_w[i0]     + ln_b[i0];
        float q1 = d1 * rstd * ln_w[i0 + 1] + ln_b[i0 + 1];
        float q2 = d2 * rstd * ln_w[i1]     + ln_b[i1];
        float q3 = d3 * rstd * ln_w[i1 + 1] + ln_b[i1 + 1];
        *(uint32_t*)&U.qn[t * 264 + i0] = pk2(q0, q1);
        *(uint32_t*)&U.qn[t * 264 + i1] = pk2(q2, q3);
    }
    __syncthreads();

    // ---- step 2: h[16 tok][64] = qn @ w1^T + b1 (waves 0..3)
    if (wv < 4) {
        int nb = wv;
        f32x4 acc = {0.0f, 0.0f, 0.0f, 0.0f};
        for (int ks = 0; ks < 8; ++ks) {
            bf16x8 afr = *(const bf16x8*)&U.qn[ln16 * 264 + ks * 32 + lq * 8];
            bf16x8 bfr = *(const bf16x8*)&w1p[(nb * 8 + ks) * 512 + lane * 8];
            acc = __builtin_amdgcn_mfma_f32_16x16x32_bf16(afr, bfr, acc, 0, 0, 0);
        }
        float bias = b1[nb * 16 + ln16];
        for (int i = 0; i < 4; ++i) {
            int t = lq * 4 + i;                      // D row = token
            G.Hb[t * 64 + nb * 16 + ln16] = f2b(acc[i] + bias);
        }
    }
    __syncthreads();

    // ---- step 3: H B-frags; sm generation -> smT; x A-frag hoist
    bf16x8 hfr[2];
    hfr[0] = *(const bf16x8*)&G.Hb[ln16 * 64 + 0 + lq * 8];
    hfr[1] = *(const bf16x8*)&G.Hb[ln16 * 64 + 32 + lq * 8];

    for (int gi = 0; gi < 8; ++gi) {                 // sm rows 16384 + g*16 + m
        int g = wv * 8 + gi;
        f32x4 acc = *(const f32x4*)&b2[16384 + g * 16 + lq * 4];
        for (int ks = 0; ks < 2; ++ks) {
            bf16x8 afr = *(const bf16x8*)&w2sp[(g * 2 + ks) * 512 + lane * 8];
            acc = __builtin_amdgcn_mfma_f32_16x16x32_bf16(afr, hfr[ks], acc, 0, 0, 0);
        }
        int o = g >> 1;
        int p0 = (g & 1) * 16 + lq * 4;
        uint2 wr;
        wr.x = pk2(acc[0], acc[1]);
        wr.y = pk2(acc[2], acc[3]);
        *(uint2*)&U.smT[ln16 * 1032 + o * 32 + p0] = wr;   // token-major
    }

    bf16x8 xa[2][2][4];                              // x A-frags [tt][p-half][ks]
    for (int tt = 0; tt < 2; ++tt) {
        const float* xp = sampled + (size_t)(tok0 + wv * 2 + tt) * 4096;
        for (int mt = 0; mt < 2; ++mt) {
            int p = mt * 16 + ln16;
            for (int ks = 0; ks < 4; ++ks) {
                int c = ks * 32 + lq * 8;
                xa[tt][mt][ks] = cvt8(*(const float4*)(xp + p * 128 + c),
                                      *(const float4*)(xp + p * 128 + c + 4));
            }
        }
    }
    __syncthreads();

    // ---- step 4: sm A-frags (K=32) for this wave's 2 tokens
    bf16x8 sa[2][2];
    for (int tt = 0; tt < 2; ++tt) {
        int t = wv * 2 + tt;
        for (int mt = 0; mt < 2; ++mt)
            sa[tt][mt] = *(const bf16x8*)&U.smT[t * 1032 + (mt * 16 + ln16) * 32 + lq * 8];
    }
    __syncthreads();    // smT dead; pt/g1s alias it from here on

    // out-projection accumulator: 16 tok x 32 q per wave (nb = 2wv, 2wv+1)
    f32x4 aco[2] = {(f32x4){0.0f, 0.0f, 0.0f, 0.0f}, (f32x4){0.0f, 0.0f, 0.0f, 0.0f}};

    // OUTACC(dt2): aco += g2t(tile dt2) @ wop. A: row=t(ln16), k=o(lq*8+j);
    // B: wop[kc5=dt2*16+d16][nb][lane][8]. Depth-1 register prefetch of the
    // wop B-frags hides L2 latency under the 2 MFMAs per step.
    auto outacc = [&](int dt2) {
        const ushort* wb = wop + ((size_t)(dt2 * 16) * 16 + wv * 2) * 512 + lane * 8;
        bf16x8 nb0 = *(const bf16x8*)(wb);
        bf16x8 nb1 = *(const bf16x8*)(wb + 512);
        for (int d16 = 0; d16 < 16; ++d16) {
            bf16x8 b0 = nb0, b1 = nb1;
            if (d16 < 15) {
                nb0 = *(const bf16x8*)(wb + (size_t)(d16 + 1) * 8192);
                nb1 = *(const bf16x8*)(wb + (size_t)(d16 + 1) * 8192 + 512);
            }
            bf16x8 afr = *(const bf16x8*)((const char*)G.g2t + g2swz(ln16, d16, lq * 16));
            aco[0] = __builtin_amdgcn_mfma_f32_16x16x32_bf16(afr, b0, aco[0], 0, 0, 0);
            aco[1] = __builtin_amdgcn_mfma_f32_16x16x32_bf16(afr, b1, aco[1], 0, 0, 0);
        }
    };

    // ---- main loop over 16 d-tiles of width 8; spatial every 2nd tile
    for (int dt = 0; dt < 16; ++dt) {
        // OUTACC for the tile completed at dt-1 (past the trailing barrier;
        // next g2t write is 2 barriers away -> race-free, overlaps GEN loads)
        if (dt && !(dt & 1)) outacc((dt >> 1) - 1);

        // GEN: wave wv owns c-block cb=wv; P[c, token] for d = dt*8+dd
        const int cb = wv;
        for (int dd = 0; dd < 8; ++dd) {
            int d = dt * 8 + dd;
            // bias: b2t[d][c], c = cb*16 + lq*4 + i -> one broadcast f32x4
            f32x4 acc = *(const f32x4*)&b2t[d * 128 + cb * 16 + lq * 4];
            for (int ks = 0; ks < 2; ++ks) {
                bf16x8 afr = *(const bf16x8*)&w2p[((cb * 128 + d) * 2 + ks) * 512 + lane * 8];
                acc = __builtin_amdgcn_mfma_f32_16x16x32_bf16(afr, hfr[ks], acc, 0, 0, 0);
            }
            // lane-linear pt: token=ln16, chunk=(c>>3)*8+dd, j=c&7
            uint2 wr;
            wr.x = pk2(acc[0], acc[1]);
            wr.y = pk2(acc[2], acc[3]);
            *(uint2*)&U.mp.pt[ln16 * 1032 + ((cb * 2 + (lq >> 1)) * 8 + dd) * 8 + (lq & 1) * 4] = wr;
        }
        __syncthreads();

        // CONSUME channel: 2 tokens per wave. Lanes n>=8 duplicate n-8's acc;
        // split gelu rows {0,1}/{2,3} across the halves (branchless).
        const int ddl = ln16 & 7;
        const bool hi = ln16 >= 8;
        for (int tt = 0; tt < 2; ++tt) {
            int t = wv * 2 + tt;
            bf16x8 bfr[4];
            for (int ks = 0; ks < 4; ++ks)
                bfr[ks] = *(const bf16x8*)&U.mp.pt[t * 1032 + (ks * 4 + lq) * 64 + ddl * 8];
            float mb = mb_s[dt * 8 + ddl];
            for (int mt = 0; mt < 2; ++mt) {
                f32x4 acc = {0.0f, 0.0f, 0.0f, 0.0f};
                for (int ks = 0; ks < 4; ++ks)
                    acc = __builtin_amdgcn_mfma_f32_16x16x32_bf16(xa[tt][mt][ks], bfr[ks], acc, 0, 0, 0);
                float va = hi ? acc[2] : acc[0];
                float vb = hi ? acc[3] : acc[1];
                float ga = gelu_fast(va + mb);
                float gb = gelu_fast(vb + mb);
                // g1s[t][d16][p]: d16 = (dt&1)*8+ddl; rows p0..p0+1 by lo half,
                // p0+2..p0+3 by hi half
                int p = mt * 16 + lq * 4 + (hi ? 2 : 0);
                *(uint32_t*)&U.mp.g1s[t * 640 + ((dt & 1) * 8 + ddl) * 40 + p] = pk2(ga, gb);
            }
        }

        // SPATIAL on odd dt: full 16-lane n over paired d16 = 0..15
        if (dt & 1) {
            __builtin_amdgcn_wave_barrier();          // order same-wave LDS W->R
            for (int tt = 0; tt < 2; ++tt) {
                int t = wv * 2 + tt;
                bf16x8 gfr = *(const bf16x8*)&U.mp.g1s[t * 640 + ln16 * 40 + lq * 8];
                for (int mt = 0; mt < 2; ++mt) {
                    f32x4 acc = {0.0f, 0.0f, 0.0f, 0.0f};
                    acc = __builtin_amdgcn_mfma_f32_16x16x32_bf16(sa[tt][mt], gfr, acc, 0, 0, 0);
                    float4 sbv = *(const float4*)&sb_s[mt * 16 + lq * 4];
                    float g0 = gelu_fast(acc[0] + sbv.x);
                    float g1 = gelu_fast(acc[1] + sbv.y);
                    float g2 = gelu_fast(acc[2] + sbv.z);
                    float g3 = gelu_fast(acc[3] + sbv.w);
                    uint2 wr;
                    wr.x = pk2(g0, g1);
                    wr.y = pk2(g2, g3);
                    // g2t[t][d16=ln16][o = mt*16+lq*4 ..+3], swizzled (8B write:
                    // byte bit3 = lq&1 untouched; XOR hits bits 4-6 only)
                    *(uint2*)((char*)G.g2t + g2swz(t, ln16, mt * 32 + lq * 8)) = wr;
                }
            }
        }
        __syncthreads();
    }

    // last g2 tile (dt2 = 7), then out = aco + bo. D row = token, col = q.
    outacc(7);
    for (int n = 0; n < 2; ++n) {
        int q = (wv * 2 + n) * 16 + ln16;
        float bv = bo[q];
        for (int i = 0; i < 4; ++i) {
            int tok = tok0 + lq * 4 + i;
            out[(size_t)tok * 256 + q] = aco[n][i] + bv;
        }
    }
}

// ---------------------------------------------------------------------------
extern "C" void kernel_launch(void* const* d_in, const int* in_sizes, int n_in,
                              void* d_out, int out_size, void* d_ws, size_t ws_size,
                              hipStream_t stream) {
    const float* sampled = (const float*)d_in[0];
    const float* query   = (const float*)d_in[1];
    const float* ln_w    = (const float*)d_in[2];
    const float* ln_b    = (const float*)d_in[3];
    const float* w1      = (const float*)d_in[4];
    const float* b1      = (const float*)d_in[5];
    const float* w2      = (const float*)d_in[6];
    const float* b2      = (const float*)d_in[7];
    const float* m_beta  = (const float*)d_in[8];
    const float* s_beta  = (const float*)d_in[9];
    const float* wo      = (const float*)d_in[10];
    const float* bo      = (const float*)d_in[11];
    float* out = (float*)d_out;

    char* ws = (char*)d_ws;
    ushort* w2p  = (ushort*)(ws);                   // 2,097,152 B
    ushort* wop  = (ushort*)(ws + 2097152);         // 2,097,152 B
    ushort* w2sp = (ushort*)(ws + 4194304);         //   131,072 B
    ushort* w1p  = (ushort*)(ws + 4325376);         //    32,768 B
    float*  b2t  = (float*) (ws + 4358144);         //    65,536 B (total ~4.4 MB)

    prep<<<1080, 256, 0, stream>>>(w2, w1, wo, b2, w2p, w2sp, w1p, wop, b2t);
    fused<<<512, 512, 0, stream>>>(sampled, query, ln_w, ln_b, b1, b2,
                                   m_beta, s_beta, w2p, w2sp, w1p, b2t,
                                   wop, bo, out);
}